// Round 11
// baseline (517.743 us; speedup 1.0000x reference)
//
#include <hip/hip_runtime.h>
#include <math.h>

#define BATCH 8
#define SEQ   2048
#define DM    256
#define DQK   128
#define NHEADS 8
#define NK    16
#define DFF   1024

typedef __attribute__((ext_vector_type(8))) short short8;
typedef __attribute__((ext_vector_type(8))) _Float16 half8;
typedef __attribute__((ext_vector_type(4))) float floatx4;

__device__ __forceinline__ unsigned short f2bf(float f) {
    unsigned int u = __float_as_uint(f);
    u += 0x7fffu + ((u >> 16) & 1u);          // round-to-nearest-even
    return (unsigned short)(u >> 16);
}

__device__ __forceinline__ float gelu_fast(float h) {
    float y = 0.7978845608028654f * (h + 0.044715f * h * h * h);
    float e = __expf(2.f * y);
    float t = 1.f - 2.f / (e + 1.f);
    return 0.5f * h * (1.f + t);
}

// ---------------------------------------------------------------------------
// Kernel W: repack W1/W2/Wv/Wo fp32 -> bf16 MFMA B-fragment order.
// ---------------------------------------------------------------------------
__global__ __launch_bounds__(256) void conv_kernel(
    const float* __restrict__ W1, const float* __restrict__ W2,
    const float* __restrict__ Wv, const float* __restrict__ Wo,
    unsigned short* __restrict__ W1f, unsigned short* __restrict__ W2f,
    unsigned short* __restrict__ Wvf, unsigned short* __restrict__ Wof)
{
    int g = blockIdx.x * 256 + threadIdx.x;
    const float* W; unsigned short* O; int e, stride;
    if (g < 32768)      { W = W1; O = W1f; e = g;         stride = DFF; }
    else if (g < 65536) { W = W2; O = W2f; e = g - 32768; stride = DM;  }
    else if (g < 73728) { W = Wv; O = Wvf; e = g - 65536; stride = DM;  }
    else                { W = Wo; O = Wof; e = g - 73728; stride = DM;  }
    int lane = e & 63;
    int kk, nt;
    if (g < 32768)      { kk = (e >> 6) & 7;  nt = e >> 9;  }
    else if (g < 65536) { kk = (e >> 6) & 31; nt = e >> 11; }
    else                { kk = (e >> 6) & 7;  nt = e >> 9;  }
    int n = nt * 16 + (lane & 15);
    int k0 = kk * 32 + (lane >> 4) * 8;
    unsigned int pk[4];
    #pragma unroll
    for (int jj = 0; jj < 4; ++jj) {
        unsigned short lo = f2bf(W[(size_t)(k0 + 2 * jj) * stride + n]);
        unsigned short hi = f2bf(W[(size_t)(k0 + 2 * jj + 1) * stride + n]);
        pk[jj] = (unsigned int)lo | ((unsigned int)hi << 16);
    }
    *(uint4*)(O + (size_t)e * 8) = make_uint4(pk[0], pk[1], pk[2], pk[3]);
}

// ---------------------------------------------------------------------------
// Kernel A1: q/k projections — VERBATIM R3-chain fp32 math (8 tokens/block).
// Outputs: qn fp32, knh/knl f16 split (R5-identical values), knsq.
// (neighbor-set safety: accumulation order unchanged)
// ---------------------------------------------------------------------------
__global__ __launch_bounds__(256) void proj_qk_kernel(
    const float* __restrict__ x,
    const float* __restrict__ Wq, const float* __restrict__ bq,
    const float* __restrict__ Wk, const float* __restrict__ bk,
    float* __restrict__ qn, _Float16* __restrict__ knh, _Float16* __restrict__ knl,
    float* __restrict__ knsq)
{
    __shared__ __align__(16) float xs[8 * 256];
    __shared__ float nred[8][2], kred[8][2], k2red[8][2];

    const int tid = threadIdx.x;
    const int b = blockIdx.x & 7;
    const int chunk = blockIdx.x >> 3;
    const size_t t0 = (size_t)b * SEQ + (size_t)chunk * 8;

    for (int i = tid; i < 8 * 256; i += 256) xs[i] = x[t0 * DM + i];
    __syncthreads();

    {
        const int col = tid & 127, half = tid >> 7;
        float qa[4] = {0.f, 0.f, 0.f, 0.f}, ka[4] = {0.f, 0.f, 0.f, 0.f};
        for (int d = 0; d < 256; ++d) {
            float wq = Wq[d * DQK + col];
            float wk = Wk[d * DQK + col];
            #pragma unroll
            for (int t = 0; t < 4; ++t) {
                float xv = xs[(half * 4 + t) * 256 + d];
                qa[t] = fmaf(xv, wq, qa[t]);
                ka[t] = fmaf(xv, wk, ka[t]);
            }
        }
        #pragma unroll
        for (int t = 0; t < 4; ++t) { qa[t] += bq[col]; ka[t] += bk[col]; }

        const int sub = (tid >> 6) & 1;
        #pragma unroll
        for (int t = 0; t < 4; ++t) {
            float sq = qa[t] * qa[t], sk = ka[t] * ka[t];
            #pragma unroll
            for (int m = 1; m < 64; m <<= 1) { sq += __shfl_xor(sq, m); sk += __shfl_xor(sk, m); }
            if ((tid & 63) == 0) { nred[half * 4 + t][sub] = sq; kred[half * 4 + t][sub] = sk; }
        }
        __syncthreads();
        float kvv[4];
        #pragma unroll
        for (int t = 0; t < 4; ++t) {
            int tok = half * 4 + t;
            float nq = sqrtf(nred[tok][0] + nred[tok][1]);
            float nk = sqrtf(kred[tok][0] + kred[tok][1]);
            float qv = qa[t] / fmaxf(nq, 1e-12f);
            float kv = ka[t] / fmaxf(nk, 1e-12f);
            qn[(t0 + tok) * DQK + col] = qv;
            _Float16 h = (_Float16)kv;
            knh[(t0 + tok) * DQK + col] = h;
            knl[(t0 + tok) * DQK + col] = (_Float16)(kv - (float)h);
            kvv[t] = kv;
        }
        #pragma unroll
        for (int t = 0; t < 4; ++t) {
            float s2 = kvv[t] * kvv[t];
            #pragma unroll
            for (int m = 1; m < 64; m <<= 1) s2 += __shfl_xor(s2, m);
            if ((tid & 63) == 0) k2red[half * 4 + t][sub] = s2;
        }
        __syncthreads();
        if (tid < 8) knsq[t0 + tid] = k2red[tid][0] + k2red[tid][1];
    }
}

// ---------------------------------------------------------------------------
// Kernel K: repack kn hi/lo rows into MFMA B-fragment order (verbatim R5).
// ---------------------------------------------------------------------------
__global__ __launch_bounds__(256) void kfrag_kernel(
    const _Float16* __restrict__ knh, const _Float16* __restrict__ knl,
    _Float16* __restrict__ knhf, _Float16* __restrict__ knlf)
{
    const int nt = blockIdx.x & 127, b = blockIdx.x >> 7;
    const int kk = threadIdx.x >> 6, lane = threadIdx.x & 63;
    const int quad = lane >> 4, lr = lane & 15;
    const size_t src = ((size_t)b * SEQ + nt * 16 + lr) * DQK + kk * 32 + quad * 8;
    const size_t dst = (((size_t)b * 128 + nt) * 4 + kk) * 512 + (size_t)lane * 8;
    *(uint4*)(knhf + dst) = *(const uint4*)(knh + src);
    *(uint4*)(knlf + dst) = *(const uint4*)(knl + src);
}

// ---------------------------------------------------------------------------
// Kernel A2: v projection via bf16 MFMA (unchanged — passing).
// ---------------------------------------------------------------------------
__global__ __launch_bounds__(256) void proj_v_kernel(
    const float* __restrict__ x,
    const float* __restrict__ bv, const float* __restrict__ g1,
    const float* __restrict__ b1,
    const unsigned short* __restrict__ Wvf, float* __restrict__ vall)
{
    __shared__ __align__(16) float xs[16][260];
    __shared__ float stat_m[16], stat_r[16];
    __shared__ float bvs[256], g1s[256], b1s[256];

    const int tid = threadIdx.x;
    const int lane = tid & 63, wave = tid >> 6;
    const int quad = lane >> 4, lr = lane & 15;
    const size_t t0 = (size_t)blockIdx.x * 16;

    for (int i = tid; i < 16 * 256; i += 256) xs[i >> 8][i & 255] = x[t0 * DM + i];
    bvs[tid] = bv[tid]; g1s[tid] = g1[tid]; b1s[tid] = b1[tid];
    __syncthreads();

    {
        int tok = tid >> 4, l = tid & 15;
        float s = 0.f, s2 = 0.f;
        #pragma unroll
        for (int i = 0; i < 16; ++i) {
            float v = xs[tok][l + 16 * i];
            s += v; s2 += v * v;
        }
        #pragma unroll
        for (int m = 1; m < 16; m <<= 1) { s += __shfl_xor(s, m); s2 += __shfl_xor(s2, m); }
        if (l == 0) {
            float mean = s * (1.f / 256.f);
            float var  = s2 * (1.f / 256.f) - mean * mean;
            stat_m[tok] = mean;
            stat_r[tok] = rsqrtf(var + 1e-5f);
        }
    }
    __syncthreads();

    short8 av[8];
    {
        float mm = stat_m[lr], rr = stat_r[lr];
        #pragma unroll
        for (int kk = 0; kk < 8; ++kk) {
            #pragma unroll
            for (int j = 0; j < 8; ++j) {
                int k = kk * 32 + quad * 8 + j;
                float v = (xs[lr][k] - mm) * rr * g1s[k] + b1s[k];
                av[kk][j] = (short)f2bf(v);
            }
        }
    }
    floatx4 acc[4];
    #pragma unroll
    for (int nt = 0; nt < 4; ++nt) acc[nt] = (floatx4){0.f, 0.f, 0.f, 0.f};
    #pragma unroll
    for (int nt = 0; nt < 4; ++nt) {
        #pragma unroll
        for (int kk = 0; kk < 8; ++kk) {
            short8 bfr = *(const short8*)(Wvf + ((size_t)(((wave * 4 + nt) * 8 + kk) * 64) + lane) * 8);
            acc[nt] = __builtin_amdgcn_mfma_f32_16x16x32_bf16(av[kk], bfr, acc[nt], 0, 0, 0);
        }
    }
    #pragma unroll
    for (int nt = 0; nt < 4; ++nt) {
        int col = (wave * 4 + nt) * 16 + lr;
        float bb = bvs[col];
        #pragma unroll
        for (int reg = 0; reg < 4; ++reg) {
            int row = quad * 4 + reg;
            vall[(t0 + row) * DM + col] = acc[nt][reg] + bb;
        }
    }
}

// ---------------------------------------------------------------------------
// Kernel B: 16 queries/block, 512 threads (8 waves).
// Phase 1: R5's EXACT f16-split MFMA score math (scores bitwise = R5's
// passing run), processed in 4 chunks of 512 keys: MFMA -> 33KB LDS chunk
// buffer -> R9-style exact scan -> 16 candidates/chunk.
// Phase 2b: exact 64-candidate merge = exact global top-16 of those scores.
// Phase 3: R4's MHA (knh+knl logits, passed) + R8's 16-row MFMA Wo (passed).
// ---------------------------------------------------------------------------
__global__ __launch_bounds__(512, 4) void attn_kernel(
    const float* __restrict__ x,
    const float* __restrict__ qn_g,
    const _Float16* __restrict__ knh, const _Float16* __restrict__ knl,
    const _Float16* __restrict__ knhf, const _Float16* __restrict__ knlf,
    const float* __restrict__ knsq_g, const float* __restrict__ vall,
    const unsigned short* __restrict__ Wof, const float* __restrict__ bo,
    const float* __restrict__ rw, float* __restrict__ out)
{
    __shared__ __align__(16) float qs[16][132];        // 8.25 KB
    __shared__ __align__(16) float s_chunk[16][516];   // 33 KB (scores, reused x4)
    __shared__ float cand_val[16][64];                 // 4 KB
    __shared__ int   cand_idx[16][64];                 // 4 KB
    __shared__ __align__(16) float attn_s[16][132];    // 8.25 KB
    __shared__ __align__(16) float o16[16][260];       // 16.25 KB
    __shared__ int gtop[16][16];                       // 1 KB  (total ~75 KB)

    const int tid = threadIdx.x;
    const int lane = tid & 63, wave = tid >> 6;
    const int quad = lane >> 4, lr = lane & 15;
    const int b = blockIdx.x & 7;
    const int chunk16 = blockIdx.x >> 3;
    const size_t tq0 = (size_t)b * SEQ + (size_t)chunk16 * 16;
    const size_t rowb = (size_t)b * SEQ;

    for (int i = tid; i < 16 * 128; i += 512)
        qs[i >> 7][i & 127] = qn_g[tq0 * DQK + i];
    __syncthreads();

    // A-fragments: f16 hi/lo split of the 16 query rows (R5-identical values)
    half8 ah[4], al[4];
    #pragma unroll
    for (int s = 0; s < 4; ++s) {
        #pragma unroll
        for (int j = 0; j < 8; ++j) {
            float v = qs[lr][s * 32 + quad * 8 + j];
            _Float16 h = (_Float16)v;
            ah[s][j] = h;
            al[s][j] = (_Float16)(v - (float)h);
        }
    }

    // ---- phases 1+2a: 4 chunks of 512 keys (32 tiles; wave does 4 tiles)
    for (int c = 0; c < 4; ++c) {
        #pragma unroll
        for (int t = 0; t < 4; ++t) {
            const int gnt = c * 32 + wave * 4 + t;          // global 16-key tile
            const _Float16* ph = knhf + ((size_t)b * 128 + gnt) * 2048 + (size_t)lane * 8;
            const _Float16* pl = knlf + ((size_t)b * 128 + gnt) * 2048 + (size_t)lane * 8;
            half8 bh0 = *(const half8*)(ph);
            half8 bh1 = *(const half8*)(ph + 512);
            half8 bh2 = *(const half8*)(ph + 1024);
            half8 bh3 = *(const half8*)(ph + 1536);
            half8 bl0 = *(const half8*)(pl);
            half8 bl1 = *(const half8*)(pl + 512);
            half8 bl2 = *(const half8*)(pl + 1024);
            half8 bl3 = *(const half8*)(pl + 1536);
            floatx4 acc = (floatx4){0.f, 0.f, 0.f, 0.f};
            // R5's exact 12-MFMA order -> scores bitwise equal R5's passing run
            acc = __builtin_amdgcn_mfma_f32_16x16x32_f16(al[0], bh0, acc, 0, 0, 0);
            acc = __builtin_amdgcn_mfma_f32_16x16x32_f16(ah[0], bl0, acc, 0, 0, 0);
            acc = __builtin_amdgcn_mfma_f32_16x16x32_f16(ah[0], bh0, acc, 0, 0, 0);
            acc = __builtin_amdgcn_mfma_f32_16x16x32_f16(al[1], bh1, acc, 0, 0, 0);
            acc = __builtin_amdgcn_mfma_f32_16x16x32_f16(ah[1], bl1, acc, 0, 0, 0);
            acc = __builtin_amdgcn_mfma_f32_16x16x32_f16(ah[1], bh1, acc, 0, 0, 0);
            acc = __builtin_amdgcn_mfma_f32_16x16x32_f16(al[2], bh2, acc, 0, 0, 0);
            acc = __builtin_amdgcn_mfma_f32_16x16x32_f16(ah[2], bl2, acc, 0, 0, 0);
            acc = __builtin_amdgcn_mfma_f32_16x16x32_f16(ah[2], bh2, acc, 0, 0, 0);
            acc = __builtin_amdgcn_mfma_f32_16x16x32_f16(al[3], bh3, acc, 0, 0, 0);
            acc = __builtin_amdgcn_mfma_f32_16x16x32_f16(ah[3], bl3, acc, 0, 0, 0);
            acc = __builtin_amdgcn_mfma_f32_16x16x32_f16(ah[3], bh3, acc, 0, 0, 0);
            const int key = gnt * 16 + lr;                  // C col = key, row = query
            const float kq = knsq_g[rowb + key];
            const int lkey = key - c * 512;
            #pragma unroll
            for (int r = 0; r < 4; ++r)
                s_chunk[quad * 4 + r][lkey] = 2.f * acc[r] - kq;
        }
        __syncthreads();

        // exact per-chunk top-16 (R9 scan); wave owns queries wave, wave+8
        for (int qq = 0; qq < 2; ++qq) {
            const int q = wave + 8 * qq;
            float v[8];
            #pragma unroll
            for (int i = 0; i < 8; ++i) v[i] = s_chunk[q][lane + 64 * i];
            for (int r = 0; r < NK; ++r) {
                float bv = v[0]; int bi = 0;
                #pragma unroll
                for (int i = 1; i < 8; ++i)
                    if (v[i] > bv) { bv = v[i]; bi = i; }   // strict: min i on tie
                int gi = c * 512 + lane + 64 * bi;
                #pragma unroll
                for (int m = 1; m < 64; m <<= 1) {
                    float ov = __shfl_xor(bv, m);
                    int   oi = __shfl_xor(gi, m);
                    if (ov > bv || (ov == bv && oi < gi)) { bv = ov; gi = oi; }
                }
                if (lane == (gi & 63)) {
                    int slot = (gi - c * 512) >> 6;
                    #pragma unroll
                    for (int i = 0; i < 8; ++i)
                        if (slot == i) v[i] = -INFINITY;
                }
                if (lane == 0) { cand_val[q][c * 16 + r] = bv; cand_idx[q][c * 16 + r] = gi; }
            }
        }
        __syncthreads();
    }

    // ---- phase 2b: exact merge of 64 candidates = exact global top-16
    for (int qq = 0; qq < 2; ++qq) {
        const int q = wave + 8 * qq;
        float mv = cand_val[q][lane];
        int   mi = cand_idx[q][lane];
        for (int r = 0; r < NK; ++r) {
            float bv = mv; int bi = mi;
            #pragma unroll
            for (int m = 1; m < 64; m <<= 1) {
                float ov = __shfl_xor(bv, m);
                int   oi = __shfl_xor(bi, m);
                if (ov > bv || (ov == bv && oi < bi)) { bv = ov; bi = oi; }
            }
            if (lane == 0) gtop[q][r] = bi;
            if (mi == bi) mv = -INFINITY;                   // unique idx: owner only
        }
    }
    __syncthreads();

    // ---- phase 3a: MHA (R4's passing code). Wave handles queries wave, wave+8.
    for (int qq = 0; qq < 2; ++qq) {
        const int q = wave + 8 * qq;
        const int h = lane >> 3;
        const int kk = lane & 7;
        const int i1 = gtop[q][kk], i2 = gtop[q][kk + 8];
        const _Float16* p1h = knh + (rowb + i1) * DQK + h * 16;
        const _Float16* p1l = knl + (rowb + i1) * DQK + h * 16;
        const _Float16* p2h = knh + (rowb + i2) * DQK + h * 16;
        const _Float16* p2l = knl + (rowb + i2) * DQK + h * 16;
        float lg1 = 0.f, lg2 = 0.f;
        #pragma unroll
        for (int d = 0; d < 16; ++d) {
            float qv = qs[q][h * 16 + d];
            lg1 = fmaf(qv, (float)p1h[d] + (float)p1l[d], lg1);
            lg2 = fmaf(qv, (float)p2h[d] + (float)p2l[d], lg2);
        }
        lg1 *= 0.25f; lg2 *= 0.25f;                          // 1/sqrt(dh=16)
        float mx = fmaxf(lg1, lg2);
        #pragma unroll
        for (int m = 1; m < 8; m <<= 1) mx = fmaxf(mx, __shfl_xor(mx, m));
        float e1 = expf(lg1 - mx), e2 = expf(lg2 - mx);
        float ssum = e1 + e2;
        #pragma unroll
        for (int m = 1; m < 8; m <<= 1) ssum += __shfl_xor(ssum, m);
        attn_s[q][h * 16 + kk] = e1 / ssum;
        attn_s[q][h * 16 + kk + 8] = e2 / ssum;
        __syncthreads();

        float o[4] = {0.f, 0.f, 0.f, 0.f};
        for (int k = 0; k < NK; ++k) {
            const float* vr = vall + (rowb + gtop[q][k]) * DM;
            #pragma unroll
            for (int j = 0; j < 4; ++j) {
                int d = lane + 64 * j;
                o[j] = fmaf(attn_s[q][(d >> 5) * 16 + k], vr[d], o[j]);
            }
        }
        #pragma unroll
        for (int j = 0; j < 4; ++j) o16[q][lane + 64 * j] = o[j];
        __syncthreads();
    }

    // ---- phase 3b: Wo via bf16 MFMA (R8's passing 16-row version; 8 waves x 2 tiles)
    {
        short8 ao[8];
        #pragma unroll
        for (int kk = 0; kk < 8; ++kk) {
            #pragma unroll
            for (int j = 0; j < 8; ++j) {
                int k = kk * 32 + quad * 8 + j;
                ao[kk][j] = (short)f2bf(o16[lr][k]);
            }
        }
        floatx4 aw[2];
        #pragma unroll
        for (int nt = 0; nt < 2; ++nt) aw[nt] = (floatx4){0.f, 0.f, 0.f, 0.f};
        #pragma unroll
        for (int nt = 0; nt < 2; ++nt) {
            #pragma unroll
            for (int kk = 0; kk < 8; ++kk) {
                short8 bofr = *(const short8*)(Wof + ((size_t)(((wave * 2 + nt) * 8 + kk) * 64) + lane) * 8);
                aw[nt] = __builtin_amdgcn_mfma_f32_16x16x32_bf16(ao[kk], bofr, aw[nt], 0, 0, 0);
            }
        }
        float rwv = rw[0];
        #pragma unroll
        for (int nt = 0; nt < 2; ++nt) {
            int col = (wave * 2 + nt) * 16 + lr;
            float bov = bo[col];
            #pragma unroll
            for (int reg = 0; reg < 4; ++reg) {
                int row = quad * 4 + reg;
                size_t t = tq0 + row;
                out[t * DM + col] = x[t * DM + col] + (aw[nt][reg] + bov) * rwv;
            }
        }
    }
}

// ---------------------------------------------------------------------------
// Kernel C: FFN via bf16 MFMA (unchanged — passing since R3).
// ---------------------------------------------------------------------------
__global__ __launch_bounds__(256, 2) void ffn_kernel(
    float* __restrict__ io,
    const float* __restrict__ gf, const float* __restrict__ bf,
    const unsigned short* __restrict__ W1f, const float* __restrict__ b1f,
    const unsigned short* __restrict__ W2f, const float* __restrict__ b2f,
    const float* __restrict__ rw)
{
    __shared__ __align__(16) float xs[16][260];
    __shared__ float gfs[256], bfs[256], b2s[256], b1s[1024];
    __shared__ float stat_m[16], stat_r[16];
    __shared__ __align__(16) unsigned short Af[8 * 64 * 8];
    __shared__ __align__(16) unsigned short G[16][1032];

    const int tid = threadIdx.x;
    const int lane = tid & 63, wave = tid >> 6;
    const int quad = lane >> 4, lr = lane & 15;
    const size_t t0 = (size_t)blockIdx.x * 16;

    for (int i = tid; i < 16 * 256; i += 256) xs[i >> 8][i & 255] = io[t0 * DM + i];
    gfs[tid] = gf[tid]; bfs[tid] = bf[tid]; b2s[tid] = b2f[tid];
    for (int i = tid; i < 1024; i += 256) b1s[i] = b1f[i];
    __syncthreads();

    {
        int tok = tid >> 4, l = tid & 15;
        float s = 0.f, s2 = 0.f;
        #pragma unroll
        for (int i = 0; i < 16; ++i) {
            float v = xs[tok][l + 16 * i];
            s += v; s2 += v * v;
        }
        #pragma unroll
        for (int m = 1; m < 16; m <<= 1) { s += __shfl_xor(s, m); s2 += __shfl_xor(s2, m); }
        if (l == 0) {
            float mean = s * (1.f / 256.f);
            float var  = s2 * (1.f / 256.f) - mean * mean;
            stat_m[tok] = mean;
            stat_r[tok] = rsqrtf(var + 1e-5f);
        }
    }
    __syncthreads();

    for (int kk = wave; kk < 8; kk += 4) {
        int m = lr, k0 = kk * 32 + quad * 8;
        float mm = stat_m[m], rr = stat_r[m];
        unsigned int pk[4];
        #pragma unroll
        for (int jj = 0; jj < 4; ++jj) {
            int ka = k0 + 2 * jj, kb = ka + 1;
            float v0 = (xs[m][ka] - mm) * rr * gfs[ka] + bfs[ka];
            float v1 = (xs[m][kb] - mm) * rr * gfs[kb] + bfs[kb];
            pk[jj] = (unsigned int)f2bf(v0) | ((unsigned int)f2bf(v1) << 16);
        }
        *(uint4*)&Af[(kk * 64 + lane) * 8] = make_uint4(pk[0], pk[1], pk[2], pk[3]);
    }
    __syncthreads();

    short8 afr[8];
    #pragma unroll
    for (int kk = 0; kk < 8; ++kk)
        afr[kk] = *(const short8*)&Af[(kk * 64 + lane) * 8];

    floatx4 acc[16];
    #pragma unroll
    for (int nt = 0; nt < 16; ++nt) acc[nt] = (floatx4){0.f, 0.f, 0.f, 0.f};

    const unsigned short* w1p = W1f + ((size_t)(wave * 16) * 8 * 64) * 8;
    for (int nt = 0; nt < 16; ++nt) {
        #pragma unroll
        for (int kk = 0; kk < 8; ++kk) {
            short8 bfr = *(const short8*)(w1p + (size_t)((nt * 8 + kk) * 64 + lane) * 8);
            acc[nt] = __builtin_amdgcn_mfma_f32_16x16x32_bf16(afr[kk], bfr, acc[nt], 0, 0, 0);
        }
    }

    #pragma unroll
    for (int nt = 0; nt < 16; ++nt) {
        #pragma unroll
        for (int reg = 0; reg < 4; ++reg) {
            int n = wave * 256 + nt * 16 + lr;
            int row = quad * 4 + reg;
            float h = acc[nt][reg] + b1s[n];
            G[row][n] = f2bf(gelu_fast(h));
        }
    }
    __syncthreads();

    floatx4 acc2[4];
    #pragma unroll
    for (int nt = 0; nt < 4; ++nt) acc2[nt] = (floatx4){0.f, 0.f, 0.f, 0.f};

    for (int kk2 = 0; kk2 < 32; ++kk2) {
        short8 a2 = *(const short8*)&G[lr][kk2 * 32 + quad * 8];
        #pragma unroll
        for (int nt = 0; nt < 4; ++nt) {
            short8 b2 = *(const short8*)(W2f + (size_t)(((wave * 4 + nt) * 32 + kk2) * 64 + lane) * 8);
            acc2[nt] = __builtin_amdgcn_mfma_f32_16x16x32_bf16(a2, b2, acc2[nt], 0, 0, 0);
        }
    }

    float rwv = rw[0];
    #pragma unroll
    for (int nt = 0; nt < 4; ++nt) {
        #pragma unroll
        for (int reg = 0; reg < 4; ++reg) {
            int col = wave * 64 + nt * 16 + lr;
            int row = quad * 4 + reg;
            float o = acc2[nt][reg] + b2s[col];
            io[(t0 + row) * DM + col] = xs[row][col] + o * rwv;
        }
    }
}

// ---------------------------------------------------------------------------
extern "C" void kernel_launch(void* const* d_in, const int* in_sizes, int n_in,
                              void* d_out, int out_size, void* d_ws, size_t ws_size,
                              hipStream_t stream)
{
    const float* x   = (const float*)d_in[0];
    const float* Wq  = (const float*)d_in[1];
    const float* bq  = (const float*)d_in[2];
    const float* Wk  = (const float*)d_in[3];
    const float* bk  = (const float*)d_in[4];
    const float* Wv  = (const float*)d_in[5];
    const float* bv  = (const float*)d_in[6];
    const float* Wo  = (const float*)d_in[7];
    const float* bo  = (const float*)d_in[8];
    const float* g1  = (const float*)d_in[9];
    const float* b1  = (const float*)d_in[10];
    const float* gf  = (const float*)d_in[11];
    const float* bf  = (const float*)d_in[12];
    const float* W1  = (const float*)d_in[13];
    const float* b1f = (const float*)d_in[14];
    const float* W2  = (const float*)d_in[15];
    const float* b2f = (const float*)d_in[16];
    const float* rw  = (const float*)d_in[17];
    float* out = (float*)d_out;

    // workspace (~41.7 MB): qn | knh | knl | knhf | knlf | vall | knsq | weights
    float* ws = (float*)d_ws;
    float* qn = ws;                                          // 2,097,152 floats
    _Float16* knh  = (_Float16*)(ws + 2097152);              // 2M halfs (1M floats)
    _Float16* knl  = (_Float16*)(ws + 3145728);              // 2M halfs
    _Float16* knhf = (_Float16*)(ws + 4194304);              // 2M halfs
    _Float16* knlf = (_Float16*)(ws + 5242880);              // 2M halfs
    float* vall = ws + 6291456;                              // 4,194,304 floats
    float* knsq = ws + 10485760;                             // 16,384 floats
    unsigned short* W1f = (unsigned short*)(ws + 10502144);  // 262,144 shorts
    unsigned short* W2f = W1f + 262144;                      // 262,144
    unsigned short* Wvf = W2f + 262144;                      // 65,536
    unsigned short* Wof = Wvf + 65536;                       // 65,536

    conv_kernel<<<320, 256, 0, stream>>>(W1, W2, Wv, Wo, W1f, W2f, Wvf, Wof);
    proj_qk_kernel<<<BATCH * SEQ / 8, 256, 0, stream>>>(x, Wq, bq, Wk, bk,
                                                        qn, knh, knl, knsq);
    kfrag_kernel<<<BATCH * 128, 256, 0, stream>>>(knh, knl, knhf, knlf);
    proj_v_kernel<<<BATCH * SEQ / 16, 256, 0, stream>>>(x, bv, g1, b1, Wvf, vall);
    attn_kernel<<<BATCH * SEQ / 16, 512, 0, stream>>>(x, qn, knh, knl, knhf, knlf,
                                                      knsq, vall, Wof, bo, rw, out);
    ffn_kernel<<<BATCH * SEQ / 16, 256, 0, stream>>>(out, gf, bf, W1f, b1f, W2f, b2f, rw);
}

// Round 12
// 438.716 us; speedup vs baseline: 1.1801x; 1.1801x over previous
//
#include <hip/hip_runtime.h>
#include <math.h>

#define BATCH 8
#define SEQ   2048
#define DM    256
#define DQK   128
#define NHEADS 8
#define NK    16
#define DFF   1024

typedef __attribute__((ext_vector_type(8))) short short8;
typedef __attribute__((ext_vector_type(4))) float floatx4;

__device__ __forceinline__ unsigned short f2bf(float f) {
    unsigned int u = __float_as_uint(f);
    u += 0x7fffu + ((u >> 16) & 1u);          // round-to-nearest-even
    return (unsigned short)(u >> 16);
}

__device__ __forceinline__ float gelu_fast(float h) {
    float y = 0.7978845608028654f * (h + 0.044715f * h * h * h);
    float e = __expf(2.f * y);
    float t = 1.f - 2.f / (e + 1.f);
    return 0.5f * h * (1.f + t);
}

// ---------------------------------------------------------------------------
// Kernel W: repack W1/W2/Wv/Wo fp32 -> bf16 MFMA B-fragment order.
// ---------------------------------------------------------------------------
__global__ __launch_bounds__(256) void conv_kernel(
    const float* __restrict__ W1, const float* __restrict__ W2,
    const float* __restrict__ Wv, const float* __restrict__ Wo,
    unsigned short* __restrict__ W1f, unsigned short* __restrict__ W2f,
    unsigned short* __restrict__ Wvf, unsigned short* __restrict__ Wof)
{
    int g = blockIdx.x * 256 + threadIdx.x;
    const float* W; unsigned short* O; int e, stride;
    if (g < 32768)      { W = W1; O = W1f; e = g;         stride = DFF; }
    else if (g < 65536) { W = W2; O = W2f; e = g - 32768; stride = DM;  }
    else if (g < 73728) { W = Wv; O = Wvf; e = g - 65536; stride = DM;  }
    else                { W = Wo; O = Wof; e = g - 73728; stride = DM;  }
    int lane = e & 63;
    int kk, nt;
    if (g < 32768)      { kk = (e >> 6) & 7;  nt = e >> 9;  }
    else if (g < 65536) { kk = (e >> 6) & 31; nt = e >> 11; }
    else                { kk = (e >> 6) & 7;  nt = e >> 9;  }
    int n = nt * 16 + (lane & 15);
    int k0 = kk * 32 + (lane >> 4) * 8;
    unsigned int pk[4];
    #pragma unroll
    for (int jj = 0; jj < 4; ++jj) {
        unsigned short lo = f2bf(W[(size_t)(k0 + 2 * jj) * stride + n]);
        unsigned short hi = f2bf(W[(size_t)(k0 + 2 * jj + 1) * stride + n]);
        pk[jj] = (unsigned int)lo | ((unsigned int)hi << 16);
    }
    *(uint4*)(O + (size_t)e * 8) = make_uint4(pk[0], pk[1], pk[2], pk[3]);
}

// ---------------------------------------------------------------------------
// Kernel A1: q/k projections — VERBATIM the R3/R7-passing fp32 chain,
// 8 tokens/block (the measured-best grouping).
// (neighbor-set safety: do NOT change any accumulation order here)
// ---------------------------------------------------------------------------
__global__ __launch_bounds__(256) void proj_qk_kernel(
    const float* __restrict__ x,
    const float* __restrict__ Wq, const float* __restrict__ bq,
    const float* __restrict__ Wk, const float* __restrict__ bk,
    float* __restrict__ qn, float* __restrict__ kn, float* __restrict__ knT,
    float* __restrict__ knsq)
{
    __shared__ __align__(16) float xs[8 * 256];
    __shared__ __align__(16) float ks[8 * 128];
    __shared__ float nred[8][2], kred[8][2], k2red[8][2];

    const int tid = threadIdx.x;
    const int b = blockIdx.x & 7;
    const int chunk = blockIdx.x >> 3;
    const size_t t0 = (size_t)b * SEQ + (size_t)chunk * 8;

    for (int i = tid; i < 8 * 256; i += 256) xs[i] = x[t0 * DM + i];
    __syncthreads();

    {
        const int col = tid & 127, half = tid >> 7;
        float qa[4] = {0.f, 0.f, 0.f, 0.f}, ka[4] = {0.f, 0.f, 0.f, 0.f};
        for (int d = 0; d < 256; ++d) {
            float wq = Wq[d * DQK + col];
            float wk = Wk[d * DQK + col];
            #pragma unroll
            for (int t = 0; t < 4; ++t) {
                float xv = xs[(half * 4 + t) * 256 + d];
                qa[t] = fmaf(xv, wq, qa[t]);
                ka[t] = fmaf(xv, wk, ka[t]);
            }
        }
        #pragma unroll
        for (int t = 0; t < 4; ++t) { qa[t] += bq[col]; ka[t] += bk[col]; }

        const int sub = (tid >> 6) & 1;
        #pragma unroll
        for (int t = 0; t < 4; ++t) {
            float sq = qa[t] * qa[t], sk = ka[t] * ka[t];
            #pragma unroll
            for (int m = 1; m < 64; m <<= 1) { sq += __shfl_xor(sq, m); sk += __shfl_xor(sk, m); }
            if ((tid & 63) == 0) { nred[half * 4 + t][sub] = sq; kred[half * 4 + t][sub] = sk; }
        }
        __syncthreads();
        float kvv[4];
        #pragma unroll
        for (int t = 0; t < 4; ++t) {
            int tok = half * 4 + t;
            float nq = sqrtf(nred[tok][0] + nred[tok][1]);
            float nk = sqrtf(kred[tok][0] + kred[tok][1]);
            float qv = qa[t] / fmaxf(nq, 1e-12f);
            float kv = ka[t] / fmaxf(nk, 1e-12f);
            qn[(t0 + tok) * DQK + col] = qv;
            kn[(t0 + tok) * DQK + col] = kv;
            ks[tok * 128 + col] = kv;
            kvv[t] = kv;
        }
        #pragma unroll
        for (int t = 0; t < 4; ++t) {
            float s2 = kvv[t] * kvv[t];
            #pragma unroll
            for (int m = 1; m < 64; m <<= 1) s2 += __shfl_xor(s2, m);
            if ((tid & 63) == 0) k2red[half * 4 + t][sub] = s2;
        }
        __syncthreads();
        if (tid < 8) knsq[t0 + tid] = k2red[tid][0] + k2red[tid][1];
    }

    if (tid < 128) {
        float tmp[8];
        #pragma unroll
        for (int t = 0; t < 8; ++t) tmp[t] = ks[t * 128 + tid];
        float* dst = knT + ((size_t)b * DQK + tid) * SEQ + (size_t)chunk * 8;
        *(float4*)(dst)     = make_float4(tmp[0], tmp[1], tmp[2], tmp[3]);
        *(float4*)(dst + 4) = make_float4(tmp[4], tmp[5], tmp[6], tmp[7]);
    }
}

// ---------------------------------------------------------------------------
// Kernel A2: v projection via bf16 MFMA (unchanged — passing).
// ---------------------------------------------------------------------------
__global__ __launch_bounds__(256) void proj_v_kernel(
    const float* __restrict__ x,
    const float* __restrict__ bv, const float* __restrict__ g1,
    const float* __restrict__ b1,
    const unsigned short* __restrict__ Wvf, float* __restrict__ vall)
{
    __shared__ __align__(16) float xs[16][260];
    __shared__ float stat_m[16], stat_r[16];
    __shared__ float bvs[256], g1s[256], b1s[256];

    const int tid = threadIdx.x;
    const int lane = tid & 63, wave = tid >> 6;
    const int quad = lane >> 4, lr = lane & 15;
    const size_t t0 = (size_t)blockIdx.x * 16;

    for (int i = tid; i < 16 * 256; i += 256) xs[i >> 8][i & 255] = x[t0 * DM + i];
    bvs[tid] = bv[tid]; g1s[tid] = g1[tid]; b1s[tid] = b1[tid];
    __syncthreads();

    {
        int tok = tid >> 4, l = tid & 15;
        float s = 0.f, s2 = 0.f;
        #pragma unroll
        for (int i = 0; i < 16; ++i) {
            float v = xs[tok][l + 16 * i];
            s += v; s2 += v * v;
        }
        #pragma unroll
        for (int m = 1; m < 16; m <<= 1) { s += __shfl_xor(s, m); s2 += __shfl_xor(s2, m); }
        if (l == 0) {
            float mean = s * (1.f / 256.f);
            float var  = s2 * (1.f / 256.f) - mean * mean;
            stat_m[tok] = mean;
            stat_r[tok] = rsqrtf(var + 1e-5f);
        }
    }
    __syncthreads();

    short8 av[8];
    {
        float mm = stat_m[lr], rr = stat_r[lr];
        #pragma unroll
        for (int kk = 0; kk < 8; ++kk) {
            #pragma unroll
            for (int j = 0; j < 8; ++j) {
                int k = kk * 32 + quad * 8 + j;
                float v = (xs[lr][k] - mm) * rr * g1s[k] + b1s[k];
                av[kk][j] = (short)f2bf(v);
            }
        }
    }
    floatx4 acc[4];
    #pragma unroll
    for (int nt = 0; nt < 4; ++nt) acc[nt] = (floatx4){0.f, 0.f, 0.f, 0.f};
    #pragma unroll
    for (int nt = 0; nt < 4; ++nt) {
        #pragma unroll
        for (int kk = 0; kk < 8; ++kk) {
            short8 bfr = *(const short8*)(Wvf + ((size_t)(((wave * 4 + nt) * 8 + kk) * 64) + lane) * 8);
            acc[nt] = __builtin_amdgcn_mfma_f32_16x16x32_bf16(av[kk], bfr, acc[nt], 0, 0, 0);
        }
    }
    #pragma unroll
    for (int nt = 0; nt < 4; ++nt) {
        int col = (wave * 4 + nt) * 16 + lr;
        float bb = bvs[col];
        #pragma unroll
        for (int reg = 0; reg < 4; ++reg) {
            int row = quad * 4 + reg;
            vall[(t0 + row) * DM + col] = acc[nt][reg] + bb;
        }
    }
}

// ---------------------------------------------------------------------------
// Kernel B: R10 attn verbatim (260us measured, passing): R7 structure +
// padded o8 (stride 260, conflict-free Wo A-pack read).
// ---------------------------------------------------------------------------
__global__ __launch_bounds__(256, 2) void attn_kernel(
    const float* __restrict__ x,
    const float* __restrict__ qn_g, const float* __restrict__ kn_g,
    const float* __restrict__ knT, const float* __restrict__ knsq_g,
    const float* __restrict__ vall,
    const unsigned short* __restrict__ Wof, const float* __restrict__ bo,
    const float* __restrict__ rw, float* __restrict__ out)
{
    __shared__ __align__(16) float s_ld[4 * SEQ];
    __shared__ __align__(16) float qs[8 * DQK];
    __shared__ __align__(16) float attn_s[8 * 128];
    __shared__ __align__(16) float o8[8 * 260];        // stride 260: conflict-free
    __shared__ int topidx[8 * NK];

    const int tid = threadIdx.x;
    const int lane = tid & 63, wave = tid >> 6;
    const int quad = lane >> 4, lr = lane & 15;
    const int b = blockIdx.x & 7;
    const int chunk = blockIdx.x >> 3;
    const size_t tq0 = (size_t)b * SEQ + (size_t)chunk * 8;
    const size_t rowb = (size_t)b * SEQ;

    *(float4*)&qs[tid * 4] = *(const float4*)&qn_g[tq0 * DQK + tid * 4];
    __syncthreads();

    float acc[8][8];
    #pragma unroll
    for (int q = 0; q < 8; ++q)
        #pragma unroll
        for (int k = 0; k < 8; ++k) acc[q][k] = 0.f;

    const float* kTb = knT + (size_t)b * DQK * SEQ;
    const int key0 = tid * 8;
    for (int d = 0; d < DQK; d += 4) {
        float kv[4][8];
        #pragma unroll
        for (int dd = 0; dd < 4; ++dd) {
            *(float4*)&kv[dd][0] = *(const float4*)&kTb[(size_t)(d + dd) * SEQ + key0];
            *(float4*)&kv[dd][4] = *(const float4*)&kTb[(size_t)(d + dd) * SEQ + key0 + 4];
        }
        #pragma unroll
        for (int q = 0; q < 8; ++q) {
            float4 qv = *(const float4*)&qs[q * DQK + d];
            float qq[4] = {qv.x, qv.y, qv.z, qv.w};
            #pragma unroll
            for (int dd = 0; dd < 4; ++dd)
                #pragma unroll
                for (int k = 0; k < 8; ++k)
                    acc[q][k] = fmaf(qq[dd], kv[dd][k], acc[q][k]);
        }
    }

    float ksq[8];
    {
        const float* ksqb = knsq_g + rowb + key0;
        float4 a = *(const float4*)(ksqb);
        float4 c = *(const float4*)(ksqb + 4);
        ksq[0] = a.x; ksq[1] = a.y; ksq[2] = a.z; ksq[3] = a.w;
        ksq[4] = c.x; ksq[5] = c.y; ksq[6] = c.z; ksq[7] = c.w;
    }

    for (int p = 0; p < 2; ++p) {
        __syncthreads();
        #pragma unroll
        for (int qq = 0; qq < 4; ++qq) {
            int q = 4 * p + qq;
            #pragma unroll
            for (int j = 0; j < 8; ++j)
                s_ld[qq * SEQ + key0 + j] = 2.f * acc[q][j] - ksq[j];
        }
        __syncthreads();
        {
            float v[32];
            #pragma unroll
            for (int i = 0; i < 32; ++i) v[i] = s_ld[wave * SEQ + lane + 64 * i];
            const int qg = 4 * p + wave;
            for (int r = 0; r < NK; ++r) {
                float bv = v[0]; int bi = 0;
                #pragma unroll
                for (int i = 1; i < 32; ++i)
                    if (v[i] > bv) { bv = v[i]; bi = i; }
                int gi = lane + 64 * bi;
                #pragma unroll
                for (int m = 1; m < 64; m <<= 1) {
                    float ov = __shfl_xor(bv, m);
                    int   oi = __shfl_xor(gi, m);
                    if (ov > bv || (ov == bv && oi < gi)) { bv = ov; gi = oi; }
                }
                if (lane == (gi & 63)) {
                    int slot = gi >> 6;
                    #pragma unroll
                    for (int i = 0; i < 32; ++i)
                        if (slot == i) v[i] = -INFINITY;
                }
                if (lane == 0) topidx[qg * NK + r] = gi;
            }
        }
    }
    __syncthreads();

    for (int qq = 0; qq < 2; ++qq) {
        const int q = wave + 4 * qq;
        const int h = lane >> 3;
        const int k1 = lane & 7, k2 = 8 + (lane & 7);
        const int i1 = topidx[q * NK + k1], i2 = topidx[q * NK + k2];
        const float* kr1 = kn_g + (rowb + i1) * DQK + h * 16;
        const float* kr2 = kn_g + (rowb + i2) * DQK + h * 16;
        float lg1 = 0.f, lg2 = 0.f;
        #pragma unroll
        for (int d = 0; d < 16; d += 4) {
            float4 qv = *(const float4*)&qs[q * DQK + h * 16 + d];
            float4 a1 = *(const float4*)&kr1[d];
            float4 a2 = *(const float4*)&kr2[d];
            lg1 = fmaf(qv.x, a1.x, lg1); lg1 = fmaf(qv.y, a1.y, lg1);
            lg1 = fmaf(qv.z, a1.z, lg1); lg1 = fmaf(qv.w, a1.w, lg1);
            lg2 = fmaf(qv.x, a2.x, lg2); lg2 = fmaf(qv.y, a2.y, lg2);
            lg2 = fmaf(qv.z, a2.z, lg2); lg2 = fmaf(qv.w, a2.w, lg2);
        }
        lg1 *= 0.25f; lg2 *= 0.25f;
        float mx = fmaxf(lg1, lg2);
        #pragma unroll
        for (int m = 1; m < 8; m <<= 1) mx = fmaxf(mx, __shfl_xor(mx, m));
        float e1 = expf(lg1 - mx), e2 = expf(lg2 - mx);
        float ssum = e1 + e2;
        #pragma unroll
        for (int m = 1; m < 8; m <<= 1) ssum += __shfl_xor(ssum, m);
        attn_s[q * 128 + h * 16 + k1] = e1 / ssum;
        attn_s[q * 128 + h * 16 + k2] = e2 / ssum;
        __syncthreads();

        float o[4] = {0.f, 0.f, 0.f, 0.f};
        for (int k = 0; k < NK; ++k) {
            const float* vr = vall + (rowb + topidx[q * NK + k]) * DM;
            #pragma unroll
            for (int j = 0; j < 4; ++j) {
                int d = lane + 64 * j;
                o[j] = fmaf(attn_s[q * 128 + (d >> 5) * 16 + k], vr[d], o[j]);
            }
        }
        #pragma unroll
        for (int j = 0; j < 4; ++j) o8[q * 260 + lane + 64 * j] = o[j];
        __syncthreads();
    }

    // ---- phase 3b: Wo via bf16 MFMA. A rows = queries 0..7 (rows 8..15 zero).
    {
        short8 ao[8];
        #pragma unroll
        for (int kk = 0; kk < 8; ++kk) {
            #pragma unroll
            for (int j = 0; j < 8; ++j) {
                int k = kk * 32 + quad * 8 + j;
                float v = (lr < 8) ? o8[lr * 260 + k] : 0.f;
                ao[kk][j] = (short)f2bf(v);
            }
        }
        floatx4 aw[4];
        #pragma unroll
        for (int nt = 0; nt < 4; ++nt) aw[nt] = (floatx4){0.f, 0.f, 0.f, 0.f};
        #pragma unroll
        for (int nt = 0; nt < 4; ++nt) {
            #pragma unroll
            for (int kk = 0; kk < 8; ++kk) {
                short8 bofr = *(const short8*)(Wof + ((size_t)(((wave * 4 + nt) * 8 + kk) * 64) + lane) * 8);
                aw[nt] = __builtin_amdgcn_mfma_f32_16x16x32_bf16(ao[kk], bofr, aw[nt], 0, 0, 0);
            }
        }
        float rwv = rw[0];
        if (quad < 2) {
            #pragma unroll
            for (int nt = 0; nt < 4; ++nt) {
                int col = (wave * 4 + nt) * 16 + lr;
                float bov = bo[col];
                #pragma unroll
                for (int reg = 0; reg < 4; ++reg) {
                    int row = quad * 4 + reg;
                    size_t t = tq0 + row;
                    out[t * DM + col] = x[t * DM + col] + (aw[nt][reg] + bov) * rwv;
                }
            }
        }
    }
}

// ---------------------------------------------------------------------------
// Kernel C: FFN via bf16 MFMA (unchanged — passing since R3).
// ---------------------------------------------------------------------------
__global__ __launch_bounds__(256, 2) void ffn_kernel(
    float* __restrict__ io,
    const float* __restrict__ gf, const float* __restrict__ bf,
    const unsigned short* __restrict__ W1f, const float* __restrict__ b1f,
    const unsigned short* __restrict__ W2f, const float* __restrict__ b2f,
    const float* __restrict__ rw)
{
    __shared__ __align__(16) float xs[16][260];
    __shared__ float gfs[256], bfs[256], b2s[256], b1s[1024];
    __shared__ float stat_m[16], stat_r[16];
    __shared__ __align__(16) unsigned short Af[8 * 64 * 8];
    __shared__ __align__(16) unsigned short G[16][1032];

    const int tid = threadIdx.x;
    const int lane = tid & 63, wave = tid >> 6;
    const int quad = lane >> 4, lr = lane & 15;
    const size_t t0 = (size_t)blockIdx.x * 16;

    for (int i = tid; i < 16 * 256; i += 256) xs[i >> 8][i & 255] = io[t0 * DM + i];
    gfs[tid] = gf[tid]; bfs[tid] = bf[tid]; b2s[tid] = b2f[tid];
    for (int i = tid; i < 1024; i += 256) b1s[i] = b1f[i];
    __syncthreads();

    {
        int tok = tid >> 4, l = tid & 15;
        float s = 0.f, s2 = 0.f;
        #pragma unroll
        for (int i = 0; i < 16; ++i) {
            float v = xs[tok][l + 16 * i];
            s += v; s2 += v * v;
        }
        #pragma unroll
        for (int m = 1; m < 16; m <<= 1) { s += __shfl_xor(s, m); s2 += __shfl_xor(s2, m); }
        if (l == 0) {
            float mean = s * (1.f / 256.f);
            float var  = s2 * (1.f / 256.f) - mean * mean;
            stat_m[tok] = mean;
            stat_r[tok] = rsqrtf(var + 1e-5f);
        }
    }
    __syncthreads();

    for (int kk = wave; kk < 8; kk += 4) {
        int m = lr, k0 = kk * 32 + quad * 8;
        float mm = stat_m[m], rr = stat_r[m];
        unsigned int pk[4];
        #pragma unroll
        for (int jj = 0; jj < 4; ++jj) {
            int ka = k0 + 2 * jj, kb = ka + 1;
            float v0 = (xs[m][ka] - mm) * rr * gfs[ka] + bfs[ka];
            float v1 = (xs[m][kb] - mm) * rr * gfs[kb] + bfs[kb];
            pk[jj] = (unsigned int)f2bf(v0) | ((unsigned int)f2bf(v1) << 16);
        }
        *(uint4*)&Af[(kk * 64 + lane) * 8] = make_uint4(pk[0], pk[1], pk[2], pk[3]);
    }
    __syncthreads();

    short8 afr[8];
    #pragma unroll
    for (int kk = 0; kk < 8; ++kk)
        afr[kk] = *(const short8*)&Af[(kk * 64 + lane) * 8];

    floatx4 acc[16];
    #pragma unroll
    for (int nt = 0; nt < 16; ++nt) acc[nt] = (floatx4){0.f, 0.f, 0.f, 0.f};

    const unsigned short* w1p = W1f + ((size_t)(wave * 16) * 8 * 64) * 8;
    for (int nt = 0; nt < 16; ++nt) {
        #pragma unroll
        for (int kk = 0; kk < 8; ++kk) {
            short8 bfr = *(const short8*)(w1p + (size_t)((nt * 8 + kk) * 64 + lane) * 8);
            acc[nt] = __builtin_amdgcn_mfma_f32_16x16x32_bf16(afr[kk], bfr, acc[nt], 0, 0, 0);
        }
    }

    #pragma unroll
    for (int nt = 0; nt < 16; ++nt) {
        #pragma unroll
        for (int reg = 0; reg < 4; ++reg) {
            int n = wave * 256 + nt * 16 + lr;
            int row = quad * 4 + reg;
            float h = acc[nt][reg] + b1s[n];
            G[row][n] = f2bf(gelu_fast(h));
        }
    }
    __syncthreads();

    floatx4 acc2[4];
    #pragma unroll
    for (int nt = 0; nt < 4; ++nt) acc2[nt] = (floatx4){0.f, 0.f, 0.f, 0.f};

    for (int kk2 = 0; kk2 < 32; ++kk2) {
        short8 a2 = *(const short8*)&G[lr][kk2 * 32 + quad * 8];
        #pragma unroll
        for (int nt = 0; nt < 4; ++nt) {
            short8 b2 = *(const short8*)(W2f + (size_t)(((wave * 4 + nt) * 32 + kk2) * 64 + lane) * 8);
            acc2[nt] = __builtin_amdgcn_mfma_f32_16x16x32_bf16(a2, b2, acc2[nt], 0, 0, 0);
        }
    }

    float rwv = rw[0];
    #pragma unroll
    for (int nt = 0; nt < 4; ++nt) {
        #pragma unroll
        for (int reg = 0; reg < 4; ++reg) {
            int col = wave * 64 + nt * 16 + lr;
            int row = quad * 4 + reg;
            float o = acc2[nt][reg] + b2s[col];
            io[(t0 + row) * DM + col] = xs[row][col] + o * rwv;
        }
    }
}

// ---------------------------------------------------------------------------
extern "C" void kernel_launch(void* const* d_in, const int* in_sizes, int n_in,
                              void* d_out, int out_size, void* d_ws, size_t ws_size,
                              hipStream_t stream)
{
    const float* x   = (const float*)d_in[0];
    const float* Wq  = (const float*)d_in[1];
    const float* bq  = (const float*)d_in[2];
    const float* Wk  = (const float*)d_in[3];
    const float* bk  = (const float*)d_in[4];
    const float* Wv  = (const float*)d_in[5];
    const float* bv  = (const float*)d_in[6];
    const float* Wo  = (const float*)d_in[7];
    const float* bo  = (const float*)d_in[8];
    const float* g1  = (const float*)d_in[9];
    const float* b1  = (const float*)d_in[10];
    const float* gf  = (const float*)d_in[11];
    const float* bf  = (const float*)d_in[12];
    const float* W1  = (const float*)d_in[13];
    const float* b1f = (const float*)d_in[14];
    const float* W2  = (const float*)d_in[15];
    const float* b2f = (const float*)d_in[16];
    const float* rw  = (const float*)d_in[17];
    float* out = (float*)d_out;

    // workspace (~43.3 MB): qn | kn | knT | vall | knsq | W1f | W2f | Wvf | Wof
    float* ws   = (float*)d_ws;
    float* qn   = ws;                          // 2,097,152 floats
    float* kn   = ws + 2097152;                // 2,097,152
    float* knT  = ws + 4194304;                // 2,097,152
    float* vall = ws + 6291456;                // 4,194,304
    float* knsq = ws + 10485760;               // 16,384
    unsigned short* W1f = (unsigned short*)(ws + 10502144);   // 262,144 shorts
    unsigned short* W2f = W1f + 262144;                       // 262,144
    unsigned short* Wvf = W2f + 262144;                       // 65,536
    unsigned short* Wof = Wvf + 65536;                        // 65,536

    conv_kernel<<<320, 256, 0, stream>>>(W1, W2, Wv, Wo, W1f, W2f, Wvf, Wof);
    proj_qk_kernel<<<BATCH * SEQ / 8, 256, 0, stream>>>(x, Wq, bq, Wk, bk,
                                                        qn, kn, knT, knsq);
    proj_v_kernel<<<BATCH * SEQ / 16, 256, 0, stream>>>(x, bv, g1, b1, Wvf, vall);
    attn_kernel<<<BATCH * SEQ / 8, 256, 0, stream>>>(x, qn, kn, knT, knsq, vall,
                                                     Wof, bo, rw, out);
    ffn_kernel<<<BATCH * SEQ / 16, 256, 0, stream>>>(out, gf, bf, W1f, b1f, W2f, b2f, rw);
}